// Round 4
// baseline (841.381 us; speedup 1.0000x reference)
//
#include <hip/hip_runtime.h>
#include <hip/hip_bf16.h>

typedef __hip_bfloat16 bf16;
typedef unsigned short u16;
typedef unsigned int u32;

#define DD 128           // feature dim
#define NG 200           // graphs
#define NL 5             // GCN layers
#define BETA_F 0.007782140442054161f   // log(1/128 + 1)
#define BN_EPS_F 1e-5f
#define WSTRIDE 136      // padded W' row stride (bf16 elems); 128x136 per layer
#define WELEMS (DD * WSTRIDE)
#define CVT_BLOCKS 1024
#define RS 136           // LDS bf16 r-tile row stride
#define TM 32            // dst rows per fused block
#define ACCS 132         // f32 acc row stride (128+4: spreads ds_add banks by row)

typedef __attribute__((ext_vector_type(8))) short bf16x8v;
typedef __attribute__((ext_vector_type(4))) float f32x4v;

// ---- dtype-generic load/store helpers (flag-selected, wave-uniform) ----

template<typename T> struct LD;
template<> struct LD<float> {
    static __device__ __forceinline__ float f(const void* p, size_t i) {
        return ((const float*)p)[i];
    }
};
template<> struct LD<bf16> {
    static __device__ __forceinline__ float f(const void* p, size_t i) {
        return __bfloat162float(((const bf16*)p)[i]);
    }
};
template<typename T> struct ST;
template<> struct ST<float> {
    static __device__ __forceinline__ void s(void* p, size_t i, float v) {
        ((float*)p)[i] = v;
    }
};
template<> struct ST<bf16> {
    static __device__ __forceinline__ void s(void* p, size_t i, float v) {
        ((bf16*)p)[i] = __float2bfloat16(v);
    }
};

// ---------------- k_init: cvt+hist (interleaved), then prepw, bounds ----------
template<typename TF>
__device__ __forceinline__ void prepw_body(int l, const void* gcn_w, const void* gcn_b,
        bf16* __restrict__ wtp, float* __restrict__ biasp) {
    int t = threadIdx.x;
    const TF* Wp = (const TF*)gcn_w + (size_t)l * DD * DD;
    const TF* bp = (const TF*)gcn_b + (size_t)l * DD;
    bf16* wo = wtp + (size_t)l * WELEMS;
    for (int idx = t; idx < DD * DD; idx += 256) {
        int k = idx >> 7, n = idx & 127;
        float wv = BETA_F * LD<TF>::f(Wp, idx) + (k == n ? (1.0f - BETA_F) : 0.0f);
        wo[n * WSTRIDE + k] = __float2bfloat16(wv);
    }
    if (t < DD) biasp[l * DD + t] = LD<TF>::f(bp, t);
}

__global__ void k_init(const int* __restrict__ src, const int* __restrict__ dst,
        int* deg_out, int* deg_in, int E, const u16* bn_g_raw, int* flag,
        const void* feat, const void* gcn_w, const void* gcn_b,
        const int* __restrict__ gid, int* gstart, bf16* wtp, float* biasp,
        bf16* hbuf, int N, int HB) {
    int b = blockIdx.x;
    int t = threadIdx.x;
    int bf = (bn_g_raw[0] == 0x3F80) ? 1 : 0;   // local detect (cached read)
    int m = (HB < CVT_BLOCKS) ? HB : CVT_BLOCKS;
    int cvtHist = CVT_BLOCKS + HB;
    if (b < cvtHist) {
        int role, rid;
        if (b < 2 * m) { role = b & 1; rid = b >> 1; }
        else { role = (HB > CVT_BLOCKS) ? 1 : 0; rid = m + (b - 2 * m); }
        if (role == 1) {
            // degree histogram: 4 edges/thread via int4, 8 fire-and-forget atomics in flight
            int i = rid * 256 + t;
            int E4 = E >> 2;
            if (i < E4) {
                int4 s4 = ((const int4*)src)[i];
                int4 d4 = ((const int4*)dst)[i];
                atomicAdd(&deg_out[s4.x], 1); atomicAdd(&deg_out[s4.y], 1);
                atomicAdd(&deg_out[s4.z], 1); atomicAdd(&deg_out[s4.w], 1);
                atomicAdd(&deg_in[d4.x], 1); atomicAdd(&deg_in[d4.y], 1);
                atomicAdd(&deg_in[d4.z], 1); atomicAdd(&deg_in[d4.w], 1);
            }
            if (rid == 0 && t == 0) {
                for (int e = E4 << 2; e < E; ++e) {
                    atomicAdd(&deg_out[src[e]], 1);
                    atomicAdd(&deg_in[dst[e]], 1);
                }
            }
        } else {
            // cvt: feat -> bf16 hbuf
            int total8 = N * DD / 8;
            int i = rid * 256 + t;
            int stride = CVT_BLOCKS * 256;
            uint4* d = (uint4*)hbuf;
            if (bf) {
                const uint4* s = (const uint4*)feat;
                for (; i < total8; i += stride) d[i] = s[i];
            } else {
                const float4* s = (const float4*)feat;
                for (; i < total8; i += stride) {
                    float4 x = s[2 * i], y = s[2 * i + 1];
                    union { uint4 u; bf16 b8[8]; } o;
                    o.b8[0] = __float2bfloat16(x.x); o.b8[1] = __float2bfloat16(x.y);
                    o.b8[2] = __float2bfloat16(x.z); o.b8[3] = __float2bfloat16(x.w);
                    o.b8[4] = __float2bfloat16(y.x); o.b8[5] = __float2bfloat16(y.y);
                    o.b8[6] = __float2bfloat16(y.z); o.b8[7] = __float2bfloat16(y.w);
                    d[i] = o.u;
                }
            }
        }
        return;
    }
    b -= cvtHist;
    if (b < NL) {
        if (bf) prepw_body<bf16 >(b, gcn_w, gcn_b, wtp, biasp);
        else    prepw_body<float>(b, gcn_w, gcn_b, wtp, biasp);
        return;
    }
    // bounds + flag
    if (t == 0) *flag = bf;
    int g = t;
    if (g <= NG) {
        if (g == NG) gstart[NG] = N;
        else {
            int lo = 0, hi = N;
            while (lo < hi) { int mid = (lo + hi) >> 1; if (gid[mid] < g) lo = mid + 1; else hi = mid; }
            gstart[g] = lo;
        }
    }
}

// ---------------- scan (3-phase) + cursor copy + norm precompute ----------------

__global__ void k_reduce_chunks(const int* __restrict__ deg, int* bsum, int N) {
    __shared__ int lds[256];
    int base = blockIdx.x * 1024;
    int s = 0;
    #pragma unroll
    for (int k = 0; k < 4; ++k) {
        int i = base + threadIdx.x + k * 256;
        if (i < N) s += deg[i];
    }
    lds[threadIdx.x] = s;
    __syncthreads();
    for (int off = 128; off > 0; off >>= 1) {
        if (threadIdx.x < off) lds[threadIdx.x] += lds[threadIdx.x + off];
        __syncthreads();
    }
    if (threadIdx.x == 0) bsum[blockIdx.x] = lds[0];
}

__global__ void k_scan_bsum(int* bsum, int B, int* row_ptr, int N, int E) {
    __shared__ int lds[128];
    int t = threadIdx.x;
    if (B > 128) {                       // fallback (not hit at this problem size)
        if (t == 0) {
            int acc = 0;
            for (int i = 0; i < B; ++i) { int v = bsum[i]; bsum[i] = acc; acc += v; }
            row_ptr[N] = E;
        }
        return;
    }
    int v = (t < B) ? bsum[t] : 0;
    lds[t] = v;
    __syncthreads();
    for (int off = 1; off < 128; off <<= 1) {
        int add = (t >= off) ? lds[t - off] : 0;
        __syncthreads();
        lds[t] += add;
        __syncthreads();
    }
    if (t < B) bsum[t] = (t > 0) ? lds[t - 1] : 0;   // exclusive
    if (t == 0) row_ptr[N] = E;
}

__global__ void k_scan_chunks(const int* __restrict__ deg_in, const int* __restrict__ deg_out,
                              const int* __restrict__ bsum, int* row_ptr, int* cursor,
                              float* norm_out, float* norm_in, int N) {
    __shared__ int lds[256];
    int t = threadIdx.x;
    int base = blockIdx.x * 1024;
    int vals[4];
    int tsum = 0;
    #pragma unroll
    for (int k = 0; k < 4; ++k) {
        int i = base + t * 4 + k;
        int v = (i < N) ? deg_in[i] : 0;
        vals[k] = tsum;
        tsum += v;
        if (i < N) {
            norm_in[i] = rsqrtf((float)(v > 1 ? v : 1));
            int doo = deg_out[i];
            norm_out[i] = rsqrtf((float)(doo > 1 ? doo : 1));
        }
    }
    lds[t] = tsum;
    __syncthreads();
    for (int off = 1; off < 256; off <<= 1) {
        int add = (t >= off) ? lds[t - off] : 0;
        __syncthreads();
        lds[t] += add;
        __syncthreads();
    }
    int toff = (t > 0 ? lds[t - 1] : 0) + bsum[blockIdx.x];
    #pragma unroll
    for (int k = 0; k < 4; ++k) {
        int i = base + t * 4 + k;
        if (i < N) { int rp = toff + vals[k]; row_ptr[i] = rp; cursor[i] = rp; }
    }
}

__global__ void k_fill_csr(const int* __restrict__ src, const int* __restrict__ dst,
                           int* cursor, int* col, int E) {
    int i = blockIdx.x * blockDim.x + threadIdx.x;
    int E4 = E >> 2;
    if (i < E4) {
        int4 s4 = ((const int4*)src)[i];
        int4 d4 = ((const int4*)dst)[i];
        int p0 = atomicAdd(&cursor[d4.x], 1);
        int p1 = atomicAdd(&cursor[d4.y], 1);
        int p2 = atomicAdd(&cursor[d4.z], 1);
        int p3 = atomicAdd(&cursor[d4.w], 1);
        col[p0] = s4.x; col[p1] = s4.y; col[p2] = s4.z; col[p3] = s4.w;
    }
    if (i == 0) {
        for (int e = E4 << 2; e < E; ++e) {
            int p = atomicAdd(&cursor[dst[e]], 1);
            col[p] = src[e];
        }
    }
}

// ---------------- fused pool / edge-parallel gather + GEMM ----------------
// blocks [0,poolCnt): pool role. blocks [poolCnt,...): TM=32 dst rows each.
// Phase A (edge-parallel): block's CSR edge range split into 16 contiguous
// sub-ranges (one per 16-lane group). Each group walks its range in 4-deep
// pipelined chunks (uniform latency hiding, no per-node serialization),
// accumulating into registers and flushing to an LDS f32 accumulator
// (ds_add_f32) on row change. Phase B: self-term + bf16 repack. Phase C:
// 32x128x128 MFMA GEMM from the LDS tile + fused column stats.
template<typename TF>
__device__ __forceinline__ void fused_body(const bf16* __restrict__ h,
        const int* __restrict__ row_ptr, const int* __restrict__ col,
        const float* __restrict__ norm_out, const float* __restrict__ norm_in,
        const float* __restrict__ statsP, const void* gamma, const void* beta,
        int apply, const int* __restrict__ gstart, float* __restrict__ pooled_l,
        int poolCnt, const bf16* __restrict__ wt, const float* __restrict__ biasf,
        bf16* __restrict__ h_out, float* __restrict__ stats, int N,
        float* s_sc, float* s_sh, int* s_rp, uint4* s_big4) {
    int t = threadIdx.x;
    if (t < DD) {
        float sc = 1.f, sh = 0.f;
        if (apply) {
            float invN = 1.0f / (float)N;
            float mu = statsP[t] * invN;
            float var = fmaxf(statsP[DD + t] * invN - mu * mu, 0.f);
            sc = rsqrtf(var + BN_EPS_F) * LD<TF>::f(gamma, t);
            sh = LD<TF>::f(beta, t) - mu * sc;
        }
        s_sc[t] = sc; s_sh[t] = sh;
    }
    __syncthreads();
    float lo = apply ? 0.f : -__builtin_inff();

    if (blockIdx.x < poolCnt) {
        // ---- pool role (red aliased into s_big4: 16*128*4 = 8KB) ----
        float (*red)[DD] = (float (*)[DD])s_big4;
        int g = blockIdx.x;
        int rlo = gstart[g], rhi = gstart[g + 1];
        int c = t & 15, rg = t >> 4;
        int d0 = c * 8;
        float sc8[8], sh8[8];
        #pragma unroll
        for (int j = 0; j < 8; ++j) { sc8[j] = s_sc[d0 + j]; sh8[j] = s_sh[d0 + j]; }
        float acc[8] = {0.f, 0.f, 0.f, 0.f, 0.f, 0.f, 0.f, 0.f};
        for (int i = rlo + rg; i < rhi; i += 16) {
            union { uint4 u; u16 us[8]; } v;
            v.u = *(const uint4*)(h + ((size_t)i << 7) + d0);
            #pragma unroll
            for (int j = 0; j < 8; ++j) {
                float f = __uint_as_float((u32)v.us[j] << 16) * sc8[j] + sh8[j];
                acc[j] += fmaxf(f, lo);
            }
        }
        #pragma unroll
        for (int j = 0; j < 8; ++j) red[rg][d0 + j] = acc[j];
        __syncthreads();
        if (t < DD) {
            float s = 0.f;
            #pragma unroll
            for (int k = 0; k < 16; ++k) s += red[k][t];
            pooled_l[g * DD + t] = s;
        }
        return;
    }

    // ---- phase A: edge-parallel gather into LDS f32 accumulator ----
    float* s_acc = (float*)s_big4;          // [TM][ACCS]
    int grp = t >> 4, c = t & 15;
    int d0 = c << 3;
    int nbase = (blockIdx.x - poolCnt) * TM;
    if (t <= TM) {
        int idx = nbase + t;
        s_rp[t] = row_ptr[idx < N ? idx : N];
    }
    for (int i = t; i < TM * ACCS; i += 256) s_acc[i] = 0.f;
    float sc8[8], sh8[8];
    #pragma unroll
    for (int j = 0; j < 8; ++j) { sc8[j] = s_sc[d0 + j]; sh8[j] = s_sh[d0 + j]; }
    __syncthreads();
    int E0 = s_rp[0], E1 = s_rp[TM];
    int cnt = E1 - E0;
    int per = (cnt + 15) >> 4;
    int ge0 = E0 + grp * per;
    int ge1 = ge0 + per; if (ge1 > E1) ge1 = E1;
    if (ge0 < ge1) {
        // start row: largest row with s_rp[row] <= ge0
        int rlo = 0, rhi = TM - 1;
        while (rlo < rhi) {
            int mid = (rlo + rhi + 1) >> 1;
            if (s_rp[mid] <= ge0) rlo = mid; else rhi = mid - 1;
        }
        int row = rlo;
        int nxt = s_rp[row + 1];
        float acc[8] = {0.f, 0.f, 0.f, 0.f, 0.f, 0.f, 0.f, 0.f};
        bool dirty = false;
        int e = ge0;
        while (e < ge1) {
            int kmax = ge1 - e; if (kmax > 4) kmax = 4;
            int cs[4]; uint4 hv[4]; float no[4];
            #pragma unroll
            for (int k = 0; k < 4; ++k) if (k < kmax) cs[k] = col[e + k];
            #pragma unroll
            for (int k = 0; k < 4; ++k) if (k < kmax)
                hv[k] = *(const uint4*)(h + ((size_t)cs[k] << 7) + d0);
            #pragma unroll
            for (int k = 0; k < 4; ++k) if (k < kmax) no[k] = norm_out[cs[k]];
            #pragma unroll
            for (int k = 0; k < 4; ++k) if (k < kmax) {
                if (e + k >= nxt) {
                    if (dirty) {
                        #pragma unroll
                        for (int j = 0; j < 8; ++j) {
                            atomicAdd(&s_acc[row * ACCS + d0 + j], acc[j]);
                            acc[j] = 0.f;
                        }
                        dirty = false;
                    }
                    do { ++row; nxt = s_rp[row + 1]; } while (e + k >= nxt);
                }
                union { uint4 u; u16 us[8]; } v;
                v.u = hv[k];
                float nn = no[k];
                #pragma unroll
                for (int j = 0; j < 8; ++j) {
                    float f = __uint_as_float((u32)v.us[j] << 16) * sc8[j] + sh8[j];
                    acc[j] += fmaxf(f, lo) * nn;
                }
                dirty = true;
            }
            e += kmax;
        }
        if (dirty) {
            #pragma unroll
            for (int j = 0; j < 8; ++j)
                atomicAdd(&s_acc[row * ACCS + d0 + j], acc[j]);
        }
    }
    __syncthreads();

    // ---- phase B: self-term + repack to bf16 tile (alias-safe via regs) ----
    uint4 sv[2];
    float rv[2][8];
    #pragma unroll
    for (int rr = 0; rr < 2; ++rr) {
        int rowl = grp * 2 + rr;
        int node = nbase + rowl;
        if (node < N) sv[rr] = *(const uint4*)(h + ((size_t)node << 7) + d0);
        #pragma unroll
        for (int j = 0; j < 8; ++j) rv[rr][j] = s_acc[rowl * ACCS + d0 + j];
    }
    __syncthreads();   // all acc reads done; tile may alias
    bf16* rt = (bf16*)s_big4;   // [TM][RS]
    #pragma unroll
    for (int rr = 0; rr < 2; ++rr) {
        int rowl = grp * 2 + rr;
        int node = nbase + rowl;
        union { uint4 u; bf16 b8[8]; } o;
        if (node < N) {
            float ni = 0.9f * norm_in[node];
            union { uint4 u; u16 us[8]; } s;
            s.u = sv[rr];
            #pragma unroll
            for (int j = 0; j < 8; ++j) {
                float f = __uint_as_float((u32)s.us[j] << 16) * sc8[j] + sh8[j];
                f = fmaxf(f, lo);
                o.b8[j] = __float2bfloat16(ni * rv[rr][j] + 0.1f * f);
            }
        } else {
            o.u = make_uint4(0u, 0u, 0u, 0u);
        }
        *(uint4*)(rt + (size_t)rowl * RS + d0) = o.u;
    }
    __syncthreads();

    // ---- phase C: GEMM from LDS tile. M=32: wave w -> rows 16*(w&1), cols 64*(w>>1)
    int w = t >> 6, lane = t & 63;
    int q = lane >> 4, cc = lane & 15;
    int rtile = w & 1;
    int chalf = w >> 1;
    f32x4v acc2[4];
    #pragma unroll
    for (int ct = 0; ct < 4; ++ct) acc2[ct] = (f32x4v){0.f, 0.f, 0.f, 0.f};
    #pragma unroll
    for (int ks = 0; ks < 4; ++ks) {
        int k0 = ks * 32 + q * 8;
        union { uint4 u; bf16x8v v; } a0;
        a0.u = *(const uint4*)(rt + (size_t)(rtile * 16 + cc) * RS + k0);
        #pragma unroll
        for (int ct = 0; ct < 4; ++ct) {
            union { uint4 u; bf16x8v v; } bb;
            bb.u = *(const uint4*)(wt + (size_t)(chalf * 64 + ct * 16 + cc) * WSTRIDE + k0);
            acc2[ct] = __builtin_amdgcn_mfma_f32_16x16x32_bf16(a0.v, bb.v, acc2[ct], 0, 0, 0);
        }
    }
    __syncthreads();   // tile reads done; safe to alias sred
    float* sred1 = (float*)s_big4;           // [2][128]
    float* sred2 = (float*)s_big4 + 2 * DD;  // [2][128]
    size_t mbase = (size_t)nbase + rtile * 16;
    // epilogue: C layout col = lane&15, row = quad*4 + reg  [m89-verified]
    float s1[4] = {0.f, 0.f, 0.f, 0.f};
    float s2[4] = {0.f, 0.f, 0.f, 0.f};
    #pragma unroll
    for (int ct = 0; ct < 4; ++ct) {
        int coln = chalf * 64 + ct * 16 + cc;
        float bs = biasf[coln];
        size_t mrow = mbase + q * 4;
        #pragma unroll
        for (int reg = 0; reg < 4; ++reg) {
            size_t row = mrow + reg;
            float v = acc2[ct][reg] + bs;
            if (row < (size_t)N) {
                h_out[(row << 7) + coln] = __float2bfloat16(v);
                s1[ct] += v;
                s2[ct] += v * v;
            }
        }
    }
    #pragma unroll
    for (int j = 0; j < 4; ++j) {
        s1[j] += __shfl_xor(s1[j], 16, 64); s1[j] += __shfl_xor(s1[j], 32, 64);
        s2[j] += __shfl_xor(s2[j], 16, 64); s2[j] += __shfl_xor(s2[j], 32, 64);
    }
    if (q == 0) {
        #pragma unroll
        for (int ct = 0; ct < 4; ++ct) {
            int coln = chalf * 64 + ct * 16 + cc;
            sred1[rtile * DD + coln] = s1[ct];
            sred2[rtile * DD + coln] = s2[ct];
        }
    }
    __syncthreads();
    if (t < DD) {
        float a1s = sred1[t] + sred1[DD + t];
        float a2s = sred2[t] + sred2[DD + t];
        atomicAdd(&stats[t], a1s);
        atomicAdd(&stats[DD + t], a2s);
    }
}

__global__ void k_fused(const bf16* __restrict__ h, const int* __restrict__ row_ptr,
        const int* __restrict__ col, const float* __restrict__ norm_out,
        const float* __restrict__ norm_in, const float* __restrict__ statsP,
        const void* bn_g, const void* bn_b, int laff, int apply,
        const int* __restrict__ gstart, float* __restrict__ pooled_l, int poolCnt,
        const int* __restrict__ flag, const bf16* __restrict__ wt,
        const float* __restrict__ biasf, bf16* __restrict__ h_out,
        float* __restrict__ stats, int N) {
    __shared__ float s_sc[DD];
    __shared__ float s_sh[DD];
    __shared__ int s_rp[TM + 1];
    __shared__ uint4 s_big4[(TM * ACCS * 4) / 16];  // 16896 B; aliased by all phases
    int bfv = *flag;
    size_t esz = bfv ? 2u : 4u;
    const char* gp = (const char*)bn_g + (size_t)laff * DD * esz;
    const char* bp = (const char*)bn_b + (size_t)laff * DD * esz;
    if (bfv) fused_body<bf16 >(h, row_ptr, col, norm_out, norm_in, statsP, gp, bp,
                               apply, gstart, pooled_l, poolCnt, wt, biasf, h_out, stats, N,
                               s_sc, s_sh, s_rp, s_big4);
    else     fused_body<float>(h, row_ptr, col, norm_out, norm_in, statsP, gp, bp,
                               apply, gstart, pooled_l, poolCnt, wt, biasf, h_out, stats, N,
                               s_sc, s_sh, s_rp, s_big4);
}

// ---------------- head (parallelized over 128 dims) ----------------

template<typename TF>
__device__ __forceinline__ void head_body(const float* __restrict__ pooled,
        const void* lin_w, const void* lin_b, void* out,
        float* red, float* scv, float* lse) {
    int g = blockIdx.x;   // 200
    int t = threadIdx.x;  // 128
    float part[10] = {0.f, 0.f, 0.f, 0.f, 0.f, 0.f, 0.f, 0.f, 0.f, 0.f};
    float mp = 0.f;
    for (int l = 0; l < NL + 1; ++l) {
        float pl = pooled[(size_t)(l * NG + g) * DD + t];
        if (l > 0) mp += pl;
        #pragma unroll
        for (int o = 0; o < 10; ++o)
            part[o] += pl * LD<TF>::f(lin_w, (size_t)l * DD * 10 + (size_t)t * 10 + o);
    }
    #pragma unroll
    for (int o = 0; o < 10; ++o) red[t * 10 + o] = part[o];
    __syncthreads();
    for (int off = 64; off >= 1; off >>= 1) {
        if (t < off) {
            #pragma unroll
            for (int o = 0; o < 10; ++o) red[t * 10 + o] += red[(t + off) * 10 + o];
        }
        __syncthreads();
    }
    if (t < 10) {
        float s = red[t];
        for (int l = 0; l < NL + 1; ++l) s += LD<TF>::f(lin_b, l * 10 + t);
        scv[t] = s;
    }
    __syncthreads();
    if (t == 0) {
        float m = scv[0];
        for (int o = 1; o < 10; ++o) m = fmaxf(m, scv[o]);
        float su = 0.f;
        for (int o = 0; o < 10; ++o) su += expf(scv[o] - m);
        *lse = m + logf(su);
    }
    __syncthreads();
    if (t < 10) ST<TF>::s(out, g * 10 + t, scv[t] - *lse);
    ST<TF>::s(out, NG * 10 + (size_t)g * DD + t, mp * 0.2f);
}

__global__ void k_head(const float* __restrict__ pooled, const int* __restrict__ flag,
        const void* lin_w, const void* lin_b, void* out) {
    __shared__ float red[128 * 10];
    __shared__ float scv[10];
    __shared__ float lse;
    if (*flag) head_body<bf16 >(pooled, lin_w, lin_b, out, red, scv, &lse);
    else       head_body<float>(pooled, lin_w, lin_b, out, red, scv, &lse);
}

// ---------------- launch ----------------

extern "C" void kernel_launch(void* const* d_in, const int* in_sizes, int n_in,
                              void* d_out, int out_size, void* d_ws, size_t ws_size,
                              hipStream_t stream) {
    const void* feat  = d_in[0];
    const int*  src   = (const int*)d_in[1];
    const int*  dst   = (const int*)d_in[2];
    const int*  gid   = (const int*)d_in[3];
    const void* gcn_w = d_in[4];
    const void* gcn_b = d_in[5];
    const void* bn_g  = d_in[6];
    const void* bn_b  = d_in[7];
    const void* lin_w = d_in[8];
    const void* lin_b = d_in[9];
    const int N = in_sizes[0] / DD;   // 100000
    const int E = in_sizes[1];        // 600000
    const int Mpad = ((N + 127) / 128) * 128;

    char* wsb = (char*)d_ws;
    size_t off = 0;
    auto carve = [&](size_t bytes) -> void* {
        void* p = wsb + off;
        off = (off + bytes + 255) & ~(size_t)255;
        return p;
    };
    int*   flag     = (int*)carve(4);
    // zeroed region: deg_out .. statsAll (one memset)
    int*   deg_out  = (int*)carve((size_t)N * 4);
    int*   deg_in   = (int*)carve((size_t)N * 4);
    float* statsAll = (float*)carve((size_t)NL * 2 * DD * 4);
    // un-zeroed scratch
    int*   row_ptr  = (int*)carve((size_t)(N + 1) * 4);
    int*   cursor   = (int*)carve((size_t)N * 4);
    int*   col      = (int*)carve((size_t)E * 4);
    int*   bsum     = (int*)carve(1024 * 4);
    int*   gstart   = (int*)carve((size_t)(NG + 1) * 4);
    float* norm_out = (float*)carve((size_t)N * 4);
    float* norm_in  = (float*)carve((size_t)N * 4);
    bf16*  wtp      = (bf16*)carve((size_t)NL * WELEMS * 2);
    float* biasp    = (float*)carve((size_t)NL * DD * 4);
    float* pooled   = (float*)carve((size_t)(NL + 1) * NG * DD * 4);
    bf16*  hA       = (bf16*)carve((size_t)Mpad * DD * 2);
    bf16*  hB       = (bf16*)carve((size_t)Mpad * DD * 2);

    if (off > ws_size) return;   // guard: leave d_out zeroed (distinguishable)

    hipMemsetAsync(deg_out, 0,
                   (size_t)((char*)statsAll - (char*)deg_out) + (size_t)NL * 2 * DD * 4,
                   stream);

    const int HB = ((E >> 2) + 255) / 256;   // hist blocks: 4 edges/thread
    k_init<<<CVT_BLOCKS + HB + NL + 1, 256, 0, stream>>>(
        src, dst, deg_out, deg_in, E, (const u16*)bn_g, flag,
        feat, gcn_w, gcn_b, gid, gstart, wtp, biasp, hA, N, HB);

    int B = (N + 1023) / 1024;
    k_reduce_chunks<<<B, 256, 0, stream>>>(deg_in, bsum, N);
    k_scan_bsum<<<1, 128, 0, stream>>>(bsum, B, row_ptr, N, E);
    k_scan_chunks<<<B, 256, 0, stream>>>(deg_in, deg_out, bsum, row_ptr, cursor,
                                         norm_out, norm_in, N);
    k_fill_csr<<<((E >> 2) + 255) / 256, 256, 0, stream>>>(src, dst, cursor, col, E);

    const int GBLK = (N + TM - 1) / TM;   // gather+gemm blocks: TM dst rows each
    bf16* bufs[2] = { hA, hB };
    for (int l = 0; l < NL; ++l) {
        bf16* hin  = bufs[l & 1];
        bf16* hout = bufs[(l + 1) & 1];
        float* stats  = statsAll + (size_t)l * 2 * DD;                      // written by layer l
        float* statsP = statsAll + (size_t)(l > 0 ? l - 1 : 0) * 2 * DD;    // prev layer's
        k_fused<<<NG + GBLK, 256, 0, stream>>>(
            hin, row_ptr, col, norm_out, norm_in, statsP, bn_g, bn_b,
            l > 0 ? l - 1 : 0, l > 0 ? 1 : 0, gstart,
            pooled + (size_t)l * NG * DD, NG, flag,
            wtp + (size_t)l * WELEMS, biasp + (size_t)l * DD, hout, stats, N);
    }

    // final pool: hidden_rep[NL] from layer NL-1 output (stats[NL-1], bn[NL-1]); pool-only grid
    k_fused<<<NG, 256, 0, stream>>>(
        bufs[NL & 1], row_ptr, col, norm_out, norm_in,
        statsAll + (size_t)(NL - 1) * 2 * DD, bn_g, bn_b, NL - 1, 1, gstart,
        pooled + (size_t)NL * NG * DD, NG, flag,
        wtp, biasp, bufs[(NL + 1) & 1], statsAll + (size_t)(NL - 1) * 2 * DD, N);

    k_head<<<NG, DD, 0, stream>>>(pooled, flag, lin_w, lin_b, d_out);
}

// Round 5
// 588.769 us; speedup vs baseline: 1.4291x; 1.4291x over previous
//
#include <hip/hip_runtime.h>
#include <hip/hip_bf16.h>

typedef __hip_bfloat16 bf16;
typedef unsigned short u16;
typedef unsigned int u32;

#define DD 128           // feature dim
#define NG 200           // graphs
#define NL 5             // GCN layers
#define BETA_F 0.007782140442054161f   // log(1/128 + 1)
#define BN_EPS_F 1e-5f
#define WSTRIDE 136      // padded W' row stride (bf16 elems); 128x136 per layer
#define WELEMS (DD * WSTRIDE)
#define CVT_BLOCKS 1024
#define RS 136           // LDS r-tile row stride (bf16 elems)
#define TM 64            // nodes per fused block (LDS tile rows) -> 18.4KB LDS
#define EC 8             // edge chunk depth (branchless, clamped padding)

typedef __attribute__((ext_vector_type(8))) short bf16x8v;
typedef __attribute__((ext_vector_type(4))) float f32x4v;

// ---- dtype-generic load/store helpers (flag-selected, wave-uniform) ----

template<typename T> struct LD;
template<> struct LD<float> {
    static __device__ __forceinline__ float f(const void* p, size_t i) {
        return ((const float*)p)[i];
    }
};
template<> struct LD<bf16> {
    static __device__ __forceinline__ float f(const void* p, size_t i) {
        return __bfloat162float(((const bf16*)p)[i]);
    }
};
template<typename T> struct ST;
template<> struct ST<float> {
    static __device__ __forceinline__ void s(void* p, size_t i, float v) {
        ((float*)p)[i] = v;
    }
};
template<> struct ST<bf16> {
    static __device__ __forceinline__ void s(void* p, size_t i, float v) {
        ((bf16*)p)[i] = __float2bfloat16(v);
    }
};

// ---------------- k_init: cvt+hist (interleaved), then prepw, bounds ----------
template<typename TF>
__device__ __forceinline__ void prepw_body(int l, const void* gcn_w, const void* gcn_b,
        bf16* __restrict__ wtp, float* __restrict__ biasp) {
    int t = threadIdx.x;
    const TF* Wp = (const TF*)gcn_w + (size_t)l * DD * DD;
    const TF* bp = (const TF*)gcn_b + (size_t)l * DD;
    bf16* wo = wtp + (size_t)l * WELEMS;
    for (int idx = t; idx < DD * DD; idx += 256) {
        int k = idx >> 7, n = idx & 127;
        float wv = BETA_F * LD<TF>::f(Wp, idx) + (k == n ? (1.0f - BETA_F) : 0.0f);
        wo[n * WSTRIDE + k] = __float2bfloat16(wv);
    }
    if (t < DD) biasp[l * DD + t] = LD<TF>::f(bp, t);
}

__global__ void k_init(const int* __restrict__ src, const int* __restrict__ dst,
        int* deg_out, int* deg_in, int E, const u16* bn_g_raw, int* flag,
        const void* feat, const void* gcn_w, const void* gcn_b,
        const int* __restrict__ gid, int* gstart, bf16* wtp, float* biasp,
        bf16* hbuf, int N, int HB) {
    int b = blockIdx.x;
    int t = threadIdx.x;
    int bf = (bn_g_raw[0] == 0x3F80) ? 1 : 0;   // local detect (cached read)
    int m = (HB < CVT_BLOCKS) ? HB : CVT_BLOCKS;
    int cvtHist = CVT_BLOCKS + HB;
    if (b < cvtHist) {
        int role, rid;
        if (b < 2 * m) { role = b & 1; rid = b >> 1; }
        else { role = (HB > CVT_BLOCKS) ? 1 : 0; rid = m + (b - 2 * m); }
        if (role == 1) {
            // degree histogram: 4 edges/thread via int4, 8 fire-and-forget atomics in flight
            int i = rid * 256 + t;
            int E4 = E >> 2;
            if (i < E4) {
                int4 s4 = ((const int4*)src)[i];
                int4 d4 = ((const int4*)dst)[i];
                atomicAdd(&deg_out[s4.x], 1); atomicAdd(&deg_out[s4.y], 1);
                atomicAdd(&deg_out[s4.z], 1); atomicAdd(&deg_out[s4.w], 1);
                atomicAdd(&deg_in[d4.x], 1); atomicAdd(&deg_in[d4.y], 1);
                atomicAdd(&deg_in[d4.z], 1); atomicAdd(&deg_in[d4.w], 1);
            }
            if (rid == 0 && t == 0) {
                for (int e = E4 << 2; e < E; ++e) {
                    atomicAdd(&deg_out[src[e]], 1);
                    atomicAdd(&deg_in[dst[e]], 1);
                }
            }
        } else {
            // cvt: feat -> bf16 hbuf
            int total8 = N * DD / 8;
            int i = rid * 256 + t;
            int stride = CVT_BLOCKS * 256;
            uint4* d = (uint4*)hbuf;
            if (bf) {
                const uint4* s = (const uint4*)feat;
                for (; i < total8; i += stride) d[i] = s[i];
            } else {
                const float4* s = (const float4*)feat;
                for (; i < total8; i += stride) {
                    float4 x = s[2 * i], y = s[2 * i + 1];
                    union { uint4 u; bf16 b8[8]; } o;
                    o.b8[0] = __float2bfloat16(x.x); o.b8[1] = __float2bfloat16(x.y);
                    o.b8[2] = __float2bfloat16(x.z); o.b8[3] = __float2bfloat16(x.w);
                    o.b8[4] = __float2bfloat16(y.x); o.b8[5] = __float2bfloat16(y.y);
                    o.b8[6] = __float2bfloat16(y.z); o.b8[7] = __float2bfloat16(y.w);
                    d[i] = o.u;
                }
            }
        }
        return;
    }
    b -= cvtHist;
    if (b < NL) {
        if (bf) prepw_body<bf16 >(b, gcn_w, gcn_b, wtp, biasp);
        else    prepw_body<float>(b, gcn_w, gcn_b, wtp, biasp);
        return;
    }
    // bounds + flag
    if (t == 0) *flag = bf;
    int g = t;
    if (g <= NG) {
        if (g == NG) gstart[NG] = N;
        else {
            int lo = 0, hi = N;
            while (lo < hi) { int mid = (lo + hi) >> 1; if (gid[mid] < g) lo = mid + 1; else hi = mid; }
            gstart[g] = lo;
        }
    }
}

// ---------------- scan (3-phase) + cursor copy + norm precompute ----------------

__global__ void k_reduce_chunks(const int* __restrict__ deg, int* bsum, int N) {
    __shared__ int lds[256];
    int base = blockIdx.x * 1024;
    int s = 0;
    #pragma unroll
    for (int k = 0; k < 4; ++k) {
        int i = base + threadIdx.x + k * 256;
        if (i < N) s += deg[i];
    }
    lds[threadIdx.x] = s;
    __syncthreads();
    for (int off = 128; off > 0; off >>= 1) {
        if (threadIdx.x < off) lds[threadIdx.x] += lds[threadIdx.x + off];
        __syncthreads();
    }
    if (threadIdx.x == 0) bsum[blockIdx.x] = lds[0];
}

__global__ void k_scan_bsum(int* bsum, int B, int* row_ptr, int N, int E) {
    __shared__ int lds[128];
    int t = threadIdx.x;
    if (B > 128) {                       // fallback (not hit at this problem size)
        if (t == 0) {
            int acc = 0;
            for (int i = 0; i < B; ++i) { int v = bsum[i]; bsum[i] = acc; acc += v; }
            row_ptr[N] = E;
        }
        return;
    }
    int v = (t < B) ? bsum[t] : 0;
    lds[t] = v;
    __syncthreads();
    for (int off = 1; off < 128; off <<= 1) {
        int add = (t >= off) ? lds[t - off] : 0;
        __syncthreads();
        lds[t] += add;
        __syncthreads();
    }
    if (t < B) bsum[t] = (t > 0) ? lds[t - 1] : 0;   // exclusive
    if (t == 0) row_ptr[N] = E;
}

__global__ void k_scan_chunks(const int* __restrict__ deg_in, const int* __restrict__ deg_out,
                              const int* __restrict__ bsum, int* row_ptr, int* cursor,
                              float* norm_out, float* norm_in, int N) {
    __shared__ int lds[256];
    int t = threadIdx.x;
    int base = blockIdx.x * 1024;
    int vals[4];
    int tsum = 0;
    #pragma unroll
    for (int k = 0; k < 4; ++k) {
        int i = base + t * 4 + k;
        int v = (i < N) ? deg_in[i] : 0;
        vals[k] = tsum;
        tsum += v;
        if (i < N) {
            norm_in[i] = rsqrtf((float)(v > 1 ? v : 1));
            int doo = deg_out[i];
            norm_out[i] = rsqrtf((float)(doo > 1 ? doo : 1));
        }
    }
    lds[t] = tsum;
    __syncthreads();
    for (int off = 1; off < 256; off <<= 1) {
        int add = (t >= off) ? lds[t - off] : 0;
        __syncthreads();
        lds[t] += add;
        __syncthreads();
    }
    int toff = (t > 0 ? lds[t - 1] : 0) + bsum[blockIdx.x];
    #pragma unroll
    for (int k = 0; k < 4; ++k) {
        int i = base + t * 4 + k;
        if (i < N) { int rp = toff + vals[k]; row_ptr[i] = rp; cursor[i] = rp; }
    }
}

__global__ void k_fill_csr(const int* __restrict__ src, const int* __restrict__ dst,
                           int* cursor, int* col, int E) {
    int i = blockIdx.x * blockDim.x + threadIdx.x;
    int E4 = E >> 2;
    if (i < E4) {
        int4 s4 = ((const int4*)src)[i];
        int4 d4 = ((const int4*)dst)[i];
        int p0 = atomicAdd(&cursor[d4.x], 1);
        int p1 = atomicAdd(&cursor[d4.y], 1);
        int p2 = atomicAdd(&cursor[d4.z], 1);
        int p3 = atomicAdd(&cursor[d4.w], 1);
        col[p0] = s4.x; col[p1] = s4.y; col[p2] = s4.z; col[p3] = s4.w;
    }
    if (i == 0) {
        for (int e = E4 << 2; e < E; ++e) {
            int p = atomicAdd(&cursor[dst[e]], 1);
            col[p] = src[e];
        }
    }
}

// ---------------- fused pool / gather+GEMM ----------------
// blocks [0,poolCnt): pool role. blocks [poolCnt,...): TM=64 nodes each.
// Phase A: 16-lane groups, node-parallel gather. Per node: uniform EC=8-deep
// branchless edge chunks (clamped index + zero-weight padding) -> 8 independent
// 256B row loads in flight, no serial remainder, no divergence. Self-row load
// issued before the edge loop to overlap. Write bf16 r-rows into LDS.
// Phase B: 4 waves run the 64x128x128 MFMA GEMM from the LDS A-tile, write
// h_out + fused column stats.
template<typename TF>
__device__ __forceinline__ void fused_body(const bf16* __restrict__ h,
        const int* __restrict__ row_ptr, const int* __restrict__ col,
        const float* __restrict__ norm_out, const float* __restrict__ norm_in,
        const float* __restrict__ statsP, const void* gamma, const void* beta,
        int apply, const int* __restrict__ gstart, float* __restrict__ pooled_l,
        int poolCnt, const bf16* __restrict__ wt, const float* __restrict__ biasf,
        bf16* __restrict__ h_out, float* __restrict__ stats, int N,
        float* s_sc, float* s_sh, uint4* s_big4) {
    int t = threadIdx.x;
    if (t < DD) {
        float sc = 1.f, sh = 0.f;
        if (apply) {
            float invN = 1.0f / (float)N;
            float mu = statsP[t] * invN;
            float var = fmaxf(statsP[DD + t] * invN - mu * mu, 0.f);
            sc = rsqrtf(var + BN_EPS_F) * LD<TF>::f(gamma, t);
            sh = LD<TF>::f(beta, t) - mu * sc;
        }
        s_sc[t] = sc; s_sh[t] = sh;
    }
    __syncthreads();
    float lo = apply ? 0.f : -__builtin_inff();

    if (blockIdx.x < poolCnt) {
        // ---- pool role (red aliased into s_big4: 16*128*4 = 8KB) ----
        float (*red)[DD] = (float (*)[DD])s_big4;
        int g = blockIdx.x;
        int rlo = gstart[g], rhi = gstart[g + 1];
        int c = t & 15, rg = t >> 4;
        int d0 = c * 8;
        float sc8[8], sh8[8];
        #pragma unroll
        for (int j = 0; j < 8; ++j) { sc8[j] = s_sc[d0 + j]; sh8[j] = s_sh[d0 + j]; }
        float acc[8] = {0.f, 0.f, 0.f, 0.f, 0.f, 0.f, 0.f, 0.f};
        for (int i = rlo + rg; i < rhi; i += 16) {
            union { uint4 u; u16 us[8]; } v;
            v.u = *(const uint4*)(h + ((size_t)i << 7) + d0);
            #pragma unroll
            for (int j = 0; j < 8; ++j) {
                float f = __uint_as_float((u32)v.us[j] << 16) * sc8[j] + sh8[j];
                acc[j] += fmaxf(f, lo);
            }
        }
        #pragma unroll
        for (int j = 0; j < 8; ++j) red[rg][d0 + j] = acc[j];
        __syncthreads();
        if (t < DD) {
            float s = 0.f;
            #pragma unroll
            for (int k = 0; k < 16; ++k) s += red[k][t];
            pooled_l[g * DD + t] = s;
        }
        return;
    }

    // ---- phase A: gather into LDS r-tile ----
    bf16* rt = (bf16*)s_big4;
    int grp = t >> 4, c = t & 15;
    int d0 = c << 3;
    float sc8[8], sh8[8];
    #pragma unroll
    for (int j = 0; j < 8; ++j) { sc8[j] = s_sc[d0 + j]; sh8[j] = s_sh[d0 + j]; }
    int nbase = (blockIdx.x - poolCnt) * TM;
    #pragma unroll 1
    for (int kk = 0; kk < TM / 16; ++kk) {
        int nl = grp + (kk << 4);        // 0..TM-1, stride-16 across groups
        int node = nbase + nl;
        union { uint4 u; bf16 b8[8]; } o;
        if (node < N) {
            int beg = row_ptr[node], end = row_ptr[node + 1];
            // self-row + norm_in issued early: overlap with edge chunk latency
            uint4 svu = *(const uint4*)(h + ((size_t)node << 7) + d0);
            float ni = 0.9f * norm_in[node];
            float acc[8] = {0.f, 0.f, 0.f, 0.f, 0.f, 0.f, 0.f, 0.f};
            #pragma unroll 1
            for (int e = beg; e < end; e += EC) {
                int cs[EC]; uint4 hv[EC]; float no[EC];
                #pragma unroll
                for (int k = 0; k < EC; ++k) {
                    int ee = e + k;
                    cs[k] = col[ee < end ? ee : end - 1];   // clamped (pad dupes last edge)
                }
                #pragma unroll
                for (int k = 0; k < EC; ++k)
                    hv[k] = *(const uint4*)(h + ((size_t)cs[k] << 7) + d0);
                #pragma unroll
                for (int k = 0; k < EC; ++k)
                    no[k] = (e + k < end) ? norm_out[cs[k]] : 0.f;  // zero-weight pad
                #pragma unroll
                for (int k = 0; k < EC; ++k) {
                    union { uint4 u; u16 us[8]; } v;
                    v.u = hv[k];
                    float nn = no[k];
                    #pragma unroll
                    for (int j = 0; j < 8; ++j) {
                        float f = __uint_as_float((u32)v.us[j] << 16) * sc8[j] + sh8[j];
                        acc[j] += fmaxf(f, lo) * nn;
                    }
                }
            }
            union { uint4 u; u16 us[8]; } sv;
            sv.u = svu;
            #pragma unroll
            for (int j = 0; j < 8; ++j) {
                float f = __uint_as_float((u32)sv.us[j] << 16) * sc8[j] + sh8[j];
                f = fmaxf(f, lo);
                o.b8[j] = __float2bfloat16(ni * acc[j] + 0.1f * f);
            }
        } else {
            o.u = make_uint4(0u, 0u, 0u, 0u);   // pad rows: zero (outputs masked anyway)
        }
        *(uint4*)(rt + (size_t)nl * RS + d0) = o.u;
    }
    __syncthreads();

    // ---- phase B: GEMM from LDS A-tile (M=64: 1 row-tile of 16 per wave) ----
    int w = t >> 6, lane = t & 63;
    int q = lane >> 4, cc = lane & 15;
    int mloc = w << 4;
    f32x4v acc2[8];
    #pragma unroll
    for (int ct = 0; ct < 8; ++ct)
        acc2[ct] = (f32x4v){0.f, 0.f, 0.f, 0.f};
    #pragma unroll
    for (int ks = 0; ks < 4; ++ks) {
        int k0 = ks * 32 + q * 8;
        union { uint4 u; bf16x8v v; } a0;
        a0.u = *(const uint4*)(rt + (size_t)(mloc + cc) * RS + k0);
        #pragma unroll
        for (int ct = 0; ct < 8; ++ct) {
            union { uint4 u; bf16x8v v; } bb;
            bb.u = *(const uint4*)(wt + (size_t)(ct * 16 + cc) * WSTRIDE + k0);
            acc2[ct] = __builtin_amdgcn_mfma_f32_16x16x32_bf16(a0.v, bb.v, acc2[ct], 0, 0, 0);
        }
    }
    __syncthreads();   // all LDS A-reads done; safe to alias sred over r-tile
    float* sred1 = (float*)s_big4;           // [4][128]
    float* sred2 = (float*)s_big4 + 4 * DD;  // [4][128]
    size_t mbase = (size_t)nbase + mloc;
    // epilogue: C layout col = lane&15, row = quad*4 + reg  [m89-verified]
    float s1[8] = {0.f, 0.f, 0.f, 0.f, 0.f, 0.f, 0.f, 0.f};
    float s2[8] = {0.f, 0.f, 0.f, 0.f, 0.f, 0.f, 0.f, 0.f};
    #pragma unroll
    for (int ct = 0; ct < 8; ++ct) {
        int coln = ct * 16 + cc;
        float bs = biasf[coln];
        size_t mrow = mbase + q * 4;
        #pragma unroll
        for (int reg = 0; reg < 4; ++reg) {
            size_t row = mrow + reg;
            float v = acc2[ct][reg] + bs;
            if (row < (size_t)N) {
                h_out[(row << 7) + coln] = __float2bfloat16(v);
                s1[ct] += v;
                s2[ct] += v * v;
            }
        }
    }
    #pragma unroll
    for (int j = 0; j < 8; ++j) {
        s1[j] += __shfl_xor(s1[j], 16, 64); s1[j] += __shfl_xor(s1[j], 32, 64);
        s2[j] += __shfl_xor(s2[j], 16, 64); s2[j] += __shfl_xor(s2[j], 32, 64);
    }
    if (q == 0) {
        #pragma unroll
        for (int ct = 0; ct < 8; ++ct) {
            sred1[w * DD + ct * 16 + cc] = s1[ct];
            sred2[w * DD + ct * 16 + cc] = s2[ct];
        }
    }
    __syncthreads();
    if (t < DD) {
        float a1s = sred1[t] + sred1[DD + t] + sred1[2 * DD + t] + sred1[3 * DD + t];
        float a2s = sred2[t] + sred2[DD + t] + sred2[2 * DD + t] + sred2[3 * DD + t];
        atomicAdd(&stats[t], a1s);
        atomicAdd(&stats[DD + t], a2s);
    }
}

__global__ void k_fused(const bf16* __restrict__ h, const int* __restrict__ row_ptr,
        const int* __restrict__ col, const float* __restrict__ norm_out,
        const float* __restrict__ norm_in, const float* __restrict__ statsP,
        const void* bn_g, const void* bn_b, int laff, int apply,
        const int* __restrict__ gstart, float* __restrict__ pooled_l, int poolCnt,
        const int* __restrict__ flag, const bf16* __restrict__ wt,
        const float* __restrict__ biasf, bf16* __restrict__ h_out,
        float* __restrict__ stats, int N) {
    __shared__ float s_sc[DD];
    __shared__ float s_sh[DD];
    __shared__ uint4 s_big4[(TM * RS * 2) / 16];   // 17408 B r-tile; aliased by pool-red & gemm-sred
    int bfv = *flag;
    size_t esz = bfv ? 2u : 4u;
    const char* gp = (const char*)bn_g + (size_t)laff * DD * esz;
    const char* bp = (const char*)bn_b + (size_t)laff * DD * esz;
    if (bfv) fused_body<bf16 >(h, row_ptr, col, norm_out, norm_in, statsP, gp, bp,
                               apply, gstart, pooled_l, poolCnt, wt, biasf, h_out, stats, N,
                               s_sc, s_sh, s_big4);
    else     fused_body<float>(h, row_ptr, col, norm_out, norm_in, statsP, gp, bp,
                               apply, gstart, pooled_l, poolCnt, wt, biasf, h_out, stats, N,
                               s_sc, s_sh, s_big4);
}

// ---------------- head (parallelized over 128 dims) ----------------

template<typename TF>
__device__ __forceinline__ void head_body(const float* __restrict__ pooled,
        const void* lin_w, const void* lin_b, void* out,
        float* red, float* scv, float* lse) {
    int g = blockIdx.x;   // 200
    int t = threadIdx.x;  // 128
    float part[10] = {0.f, 0.f, 0.f, 0.f, 0.f, 0.f, 0.f, 0.f, 0.f, 0.f};
    float mp = 0.f;
    for (int l = 0; l < NL + 1; ++l) {
        float pl = pooled[(size_t)(l * NG + g) * DD + t];
        if (l > 0) mp += pl;
        #pragma unroll
        for (int o = 0; o < 10; ++o)
            part[o] += pl * LD<TF>::f(lin_w, (size_t)l * DD * 10 + (size_t)t * 10 + o);
    }
    #pragma unroll
    for (int o = 0; o < 10; ++o) red[t * 10 + o] = part[o];
    __syncthreads();
    for (int off = 64; off >= 1; off >>= 1) {
        if (t < off) {
            #pragma unroll
            for (int o = 0; o < 10; ++o) red[t * 10 + o] += red[(t + off) * 10 + o];
        }
        __syncthreads();
    }
    if (t < 10) {
        float s = red[t];
        for (int l = 0; l < NL + 1; ++l) s += LD<TF>::f(lin_b, l * 10 + t);
        scv[t] = s;
    }
    __syncthreads();
    if (t == 0) {
        float m = scv[0];
        for (int o = 1; o < 10; ++o) m = fmaxf(m, scv[o]);
        float su = 0.f;
        for (int o = 0; o < 10; ++o) su += expf(scv[o] - m);
        *lse = m + logf(su);
    }
    __syncthreads();
    if (t < 10) ST<TF>::s(out, g * 10 + t, scv[t] - *lse);
    ST<TF>::s(out, NG * 10 + (size_t)g * DD + t, mp * 0.2f);
}

__global__ void k_head(const float* __restrict__ pooled, const int* __restrict__ flag,
        const void* lin_w, const void* lin_b, void* out) {
    __shared__ float red[128 * 10];
    __shared__ float scv[10];
    __shared__ float lse;
    if (*flag) head_body<bf16 >(pooled, lin_w, lin_b, out, red, scv, &lse);
    else       head_body<float>(pooled, lin_w, lin_b, out, red, scv, &lse);
}

// ---------------- launch ----------------

extern "C" void kernel_launch(void* const* d_in, const int* in_sizes, int n_in,
                              void* d_out, int out_size, void* d_ws, size_t ws_size,
                              hipStream_t stream) {
    const void* feat  = d_in[0];
    const int*  src   = (const int*)d_in[1];
    const int*  dst   = (const int*)d_in[2];
    const int*  gid   = (const int*)d_in[3];
    const void* gcn_w = d_in[4];
    const void* gcn_b = d_in[5];
    const void* bn_g  = d_in[6];
    const void* bn_b  = d_in[7];
    const void* lin_w = d_in[8];
    const void* lin_b = d_in[9];
    const int N = in_sizes[0] / DD;   // 100000
    const int E = in_sizes[1];        // 600000
    const int Mpad = ((N + 127) / 128) * 128;

    char* wsb = (char*)d_ws;
    size_t off = 0;
    auto carve = [&](size_t bytes) -> void* {
        void* p = wsb + off;
        off = (off + bytes + 255) & ~(size_t)255;
        return p;
    };
    int*   flag     = (int*)carve(4);
    // zeroed region: deg_out .. statsAll (one memset)
    int*   deg_out  = (int*)carve((size_t)N * 4);
    int*   deg_in   = (int*)carve((size_t)N * 4);
    float* statsAll = (float*)carve((size_t)NL * 2 * DD * 4);
    // un-zeroed scratch
    int*   row_ptr  = (int*)carve((size_t)(N + 1) * 4);
    int*   cursor   = (int*)carve((size_t)N * 4);
    int*   col      = (int*)carve((size_t)E * 4);
    int*   bsum     = (int*)carve(1024 * 4);
    int*   gstart   = (int*)carve((size_t)(NG + 1) * 4);
    float* norm_out = (float*)carve((size_t)N * 4);
    float* norm_in  = (float*)carve((size_t)N * 4);
    bf16*  wtp      = (bf16*)carve((size_t)NL * WELEMS * 2);
    float* biasp    = (float*)carve((size_t)NL * DD * 4);
    float* pooled   = (float*)carve((size_t)(NL + 1) * NG * DD * 4);
    bf16*  hA       = (bf16*)carve((size_t)Mpad * DD * 2);
    bf16*  hB       = (bf16*)carve((size_t)Mpad * DD * 2);

    if (off > ws_size) return;   // guard: leave d_out zeroed (distinguishable)

    hipMemsetAsync(deg_out, 0,
                   (size_t)((char*)statsAll - (char*)deg_out) + (size_t)NL * 2 * DD * 4,
                   stream);

    const int HB = ((E >> 2) + 255) / 256;   // hist blocks: 4 edges/thread
    k_init<<<CVT_BLOCKS + HB + NL + 1, 256, 0, stream>>>(
        src, dst, deg_out, deg_in, E, (const u16*)bn_g, flag,
        feat, gcn_w, gcn_b, gid, gstart, wtp, biasp, hA, N, HB);

    int B = (N + 1023) / 1024;
    k_reduce_chunks<<<B, 256, 0, stream>>>(deg_in, bsum, N);
    k_scan_bsum<<<1, 128, 0, stream>>>(bsum, B, row_ptr, N, E);
    k_scan_chunks<<<B, 256, 0, stream>>>(deg_in, deg_out, bsum, row_ptr, cursor,
                                         norm_out, norm_in, N);
    k_fill_csr<<<((E >> 2) + 255) / 256, 256, 0, stream>>>(src, dst, cursor, col, E);

    const int GBLK = (N + TM - 1) / TM;   // gather+gemm blocks: TM nodes each
    bf16* bufs[2] = { hA, hB };
    for (int l = 0; l < NL; ++l) {
        bf16* hin  = bufs[l & 1];
        bf16* hout = bufs[(l + 1) & 1];
        float* stats  = statsAll + (size_t)l * 2 * DD;                      // written by layer l
        float* statsP = statsAll + (size_t)(l > 0 ? l - 1 : 0) * 2 * DD;    // prev layer's
        k_fused<<<NG + GBLK, 256, 0, stream>>>(
            hin, row_ptr, col, norm_out, norm_in, statsP, bn_g, bn_b,
            l > 0 ? l - 1 : 0, l > 0 ? 1 : 0, gstart,
            pooled + (size_t)l * NG * DD, NG, flag,
            wtp + (size_t)l * WELEMS, biasp + (size_t)l * DD, hout, stats, N);
    }

    // final pool: hidden_rep[NL] from layer NL-1 output (stats[NL-1], bn[NL-1]); pool-only grid
    k_fused<<<NG, 256, 0, stream>>>(
        bufs[NL & 1], row_ptr, col, norm_out, norm_in,
        statsAll + (size_t)(NL - 1) * 2 * DD, bn_g, bn_b, NL - 1, 1, gstart,
        pooled + (size_t)NL * NG * DD, NG, flag,
        wtp, biasp, bufs[(NL + 1) & 1], statsAll + (size_t)(NL - 1) * 2 * DD, N);

    k_head<<<NG, DD, 0, stream>>>(pooled, flag, lin_w, lin_b, d_out);
}

// Round 6
// 536.110 us; speedup vs baseline: 1.5694x; 1.0982x over previous
//
#include <hip/hip_runtime.h>
#include <hip/hip_bf16.h>

typedef __hip_bfloat16 bf16;
typedef unsigned short u16;
typedef unsigned int u32;

#define DD 128           // feature dim
#define NG 200           // graphs
#define NL 5             // GCN layers
#define BETA_F 0.007782140442054161f   // log(1/128 + 1)
#define BN_EPS_F 1e-5f
#define WSTRIDE 136      // padded W' row stride (bf16 elems); 128x136 per layer
#define WELEMS (DD * WSTRIDE)
#define CVT_BLOCKS 1024
#define RS 136           // LDS r-tile row stride (bf16 elems)
#define TM 16            // nodes per fused block: ONE node per 16-lane group (no serial kk loop)
#define EC 8             // edge chunk depth (branchless, clamped padding)
#define NREP 8           // stats replication factor (atomic contention spread)

typedef __attribute__((ext_vector_type(8))) short bf16x8v;
typedef __attribute__((ext_vector_type(4))) float f32x4v;

// ---- dtype-generic load/store helpers (flag-selected, wave-uniform) ----

template<typename T> struct LD;
template<> struct LD<float> {
    static __device__ __forceinline__ float f(const void* p, size_t i) {
        return ((const float*)p)[i];
    }
};
template<> struct LD<bf16> {
    static __device__ __forceinline__ float f(const void* p, size_t i) {
        return __bfloat162float(((const bf16*)p)[i]);
    }
};
template<typename T> struct ST;
template<> struct ST<float> {
    static __device__ __forceinline__ void s(void* p, size_t i, float v) {
        ((float*)p)[i] = v;
    }
};
template<> struct ST<bf16> {
    static __device__ __forceinline__ void s(void* p, size_t i, float v) {
        ((bf16*)p)[i] = __float2bfloat16(v);
    }
};

// ---------------- k_init: cvt+hist (interleaved), then prepw, bounds ----------
template<typename TF>
__device__ __forceinline__ void prepw_body(int l, const void* gcn_w, const void* gcn_b,
        bf16* __restrict__ wtp, float* __restrict__ biasp) {
    int t = threadIdx.x;
    const TF* Wp = (const TF*)gcn_w + (size_t)l * DD * DD;
    const TF* bp = (const TF*)gcn_b + (size_t)l * DD;
    bf16* wo = wtp + (size_t)l * WELEMS;
    for (int idx = t; idx < DD * DD; idx += 256) {
        int k = idx >> 7, n = idx & 127;
        float wv = BETA_F * LD<TF>::f(Wp, idx) + (k == n ? (1.0f - BETA_F) : 0.0f);
        wo[n * WSTRIDE + k] = __float2bfloat16(wv);
    }
    if (t < DD) biasp[l * DD + t] = LD<TF>::f(bp, t);
}

__global__ void k_init(const int* __restrict__ src, const int* __restrict__ dst,
        int* deg_out, int* deg_in, int E, const u16* bn_g_raw, int* flag,
        const void* feat, const void* gcn_w, const void* gcn_b,
        const int* __restrict__ gid, int* gstart, bf16* wtp, float* biasp,
        bf16* hbuf, int N, int HB) {
    int b = blockIdx.x;
    int t = threadIdx.x;
    int bf = (bn_g_raw[0] == 0x3F80) ? 1 : 0;   // local detect (cached read)
    int m = (HB < CVT_BLOCKS) ? HB : CVT_BLOCKS;
    int cvtHist = CVT_BLOCKS + HB;
    if (b < cvtHist) {
        int role, rid;
        if (b < 2 * m) { role = b & 1; rid = b >> 1; }
        else { role = (HB > CVT_BLOCKS) ? 1 : 0; rid = m + (b - 2 * m); }
        if (role == 1) {
            // degree histogram: 4 edges/thread via int4, 8 fire-and-forget atomics in flight
            int i = rid * 256 + t;
            int E4 = E >> 2;
            if (i < E4) {
                int4 s4 = ((const int4*)src)[i];
                int4 d4 = ((const int4*)dst)[i];
                atomicAdd(&deg_out[s4.x], 1); atomicAdd(&deg_out[s4.y], 1);
                atomicAdd(&deg_out[s4.z], 1); atomicAdd(&deg_out[s4.w], 1);
                atomicAdd(&deg_in[d4.x], 1); atomicAdd(&deg_in[d4.y], 1);
                atomicAdd(&deg_in[d4.z], 1); atomicAdd(&deg_in[d4.w], 1);
            }
            if (rid == 0 && t == 0) {
                for (int e = E4 << 2; e < E; ++e) {
                    atomicAdd(&deg_out[src[e]], 1);
                    atomicAdd(&deg_in[dst[e]], 1);
                }
            }
        } else {
            // cvt: feat -> bf16 hbuf
            int total8 = N * DD / 8;
            int i = rid * 256 + t;
            int stride = CVT_BLOCKS * 256;
            uint4* d = (uint4*)hbuf;
            if (bf) {
                const uint4* s = (const uint4*)feat;
                for (; i < total8; i += stride) d[i] = s[i];
            } else {
                const float4* s = (const float4*)feat;
                for (; i < total8; i += stride) {
                    float4 x = s[2 * i], y = s[2 * i + 1];
                    union { uint4 u; bf16 b8[8]; } o;
                    o.b8[0] = __float2bfloat16(x.x); o.b8[1] = __float2bfloat16(x.y);
                    o.b8[2] = __float2bfloat16(x.z); o.b8[3] = __float2bfloat16(x.w);
                    o.b8[4] = __float2bfloat16(y.x); o.b8[5] = __float2bfloat16(y.y);
                    o.b8[6] = __float2bfloat16(y.z); o.b8[7] = __float2bfloat16(y.w);
                    d[i] = o.u;
                }
            }
        }
        return;
    }
    b -= cvtHist;
    if (b < NL) {
        if (bf) prepw_body<bf16 >(b, gcn_w, gcn_b, wtp, biasp);
        else    prepw_body<float>(b, gcn_w, gcn_b, wtp, biasp);
        return;
    }
    // bounds + flag
    if (t == 0) *flag = bf;
    int g = t;
    if (g <= NG) {
        if (g == NG) gstart[NG] = N;
        else {
            int lo = 0, hi = N;
            while (lo < hi) { int mid = (lo + hi) >> 1; if (gid[mid] < g) lo = mid + 1; else hi = mid; }
            gstart[g] = lo;
        }
    }
}

// ---------------- scan (3-phase) + cursor copy + norm precompute ----------------

__global__ void k_reduce_chunks(const int* __restrict__ deg, int* bsum, int N) {
    __shared__ int lds[256];
    int base = blockIdx.x * 1024;
    int s = 0;
    #pragma unroll
    for (int k = 0; k < 4; ++k) {
        int i = base + threadIdx.x + k * 256;
        if (i < N) s += deg[i];
    }
    lds[threadIdx.x] = s;
    __syncthreads();
    for (int off = 128; off > 0; off >>= 1) {
        if (threadIdx.x < off) lds[threadIdx.x] += lds[threadIdx.x + off];
        __syncthreads();
    }
    if (threadIdx.x == 0) bsum[blockIdx.x] = lds[0];
}

__global__ void k_scan_bsum(int* bsum, int B, int* row_ptr, int N, int E) {
    __shared__ int lds[128];
    int t = threadIdx.x;
    if (B > 128) {                       // fallback (not hit at this problem size)
        if (t == 0) {
            int acc = 0;
            for (int i = 0; i < B; ++i) { int v = bsum[i]; bsum[i] = acc; acc += v; }
            row_ptr[N] = E;
        }
        return;
    }
    int v = (t < B) ? bsum[t] : 0;
    lds[t] = v;
    __syncthreads();
    for (int off = 1; off < 128; off <<= 1) {
        int add = (t >= off) ? lds[t - off] : 0;
        __syncthreads();
        lds[t] += add;
        __syncthreads();
    }
    if (t < B) bsum[t] = (t > 0) ? lds[t - 1] : 0;   // exclusive
    if (t == 0) row_ptr[N] = E;
}

__global__ void k_scan_chunks(const int* __restrict__ deg_in, const int* __restrict__ deg_out,
                              const int* __restrict__ bsum, int* row_ptr, int* cursor,
                              float* norm_out, float* norm_in, int N) {
    __shared__ int lds[256];
    int t = threadIdx.x;
    int base = blockIdx.x * 1024;
    int vals[4];
    int tsum = 0;
    #pragma unroll
    for (int k = 0; k < 4; ++k) {
        int i = base + t * 4 + k;
        int v = (i < N) ? deg_in[i] : 0;
        vals[k] = tsum;
        tsum += v;
        if (i < N) {
            norm_in[i] = rsqrtf((float)(v > 1 ? v : 1));
            int doo = deg_out[i];
            norm_out[i] = rsqrtf((float)(doo > 1 ? doo : 1));
        }
    }
    lds[t] = tsum;
    __syncthreads();
    for (int off = 1; off < 256; off <<= 1) {
        int add = (t >= off) ? lds[t - off] : 0;
        __syncthreads();
        lds[t] += add;
        __syncthreads();
    }
    int toff = (t > 0 ? lds[t - 1] : 0) + bsum[blockIdx.x];
    #pragma unroll
    for (int k = 0; k < 4; ++k) {
        int i = base + t * 4 + k;
        if (i < N) { int rp = toff + vals[k]; row_ptr[i] = rp; cursor[i] = rp; }
    }
}

__global__ void k_fill_csr(const int* __restrict__ src, const int* __restrict__ dst,
                           int* cursor, int* col, int E) {
    int i = blockIdx.x * blockDim.x + threadIdx.x;
    int E4 = E >> 2;
    if (i < E4) {
        int4 s4 = ((const int4*)src)[i];
        int4 d4 = ((const int4*)dst)[i];
        int p0 = atomicAdd(&cursor[d4.x], 1);
        int p1 = atomicAdd(&cursor[d4.y], 1);
        int p2 = atomicAdd(&cursor[d4.z], 1);
        int p3 = atomicAdd(&cursor[d4.w], 1);
        col[p0] = s4.x; col[p1] = s4.y; col[p2] = s4.z; col[p3] = s4.w;
    }
    if (i == 0) {
        for (int e = E4 << 2; e < E; ++e) {
            int p = atomicAdd(&cursor[dst[e]], 1);
            col[p] = src[e];
        }
    }
}

// ---------------- fused pool / gather+GEMM ----------------
// blocks [0,poolCnt): pool role. blocks [poolCnt,...): TM=16 nodes each,
// ONE node per 16-lane group — no serial node loop, max chunk chains in flight.
// Phase A: per node, uniform EC=8-deep branchless edge chunks (clamped index +
// zero-weight padding) -> 8 independent 256B row loads in flight. Write bf16
// r-rows into LDS. Phase B: 4 waves run the 16x128x128 MFMA GEMM (wave w owns
// cols [32w,32w+32)), write h_out + column stats via 8-way-replicated atomics.
// Stats layout: [NREP][2][DD] per layer; consumers sum the NREP replicas.
template<typename TF>
__device__ __forceinline__ void fused_body(const bf16* __restrict__ h,
        const int* __restrict__ row_ptr, const int* __restrict__ col,
        const float* __restrict__ norm_out, const float* __restrict__ norm_in,
        const float* __restrict__ statsP, const void* gamma, const void* beta,
        int apply, const int* __restrict__ gstart, float* __restrict__ pooled_l,
        int poolCnt, const bf16* __restrict__ wt, const float* __restrict__ biasf,
        bf16* __restrict__ h_out, float* __restrict__ stats, int N,
        float* s_sc, float* s_sh, uint4* s_big4) {
    int t = threadIdx.x;
    if (t < DD) {
        float sc = 1.f, sh = 0.f;
        if (apply) {
            float m1 = 0.f, m2 = 0.f;
            #pragma unroll
            for (int r = 0; r < NREP; ++r) {
                m1 += statsP[r * 2 * DD + t];
                m2 += statsP[r * 2 * DD + DD + t];
            }
            float invN = 1.0f / (float)N;
            float mu = m1 * invN;
            float var = fmaxf(m2 * invN - mu * mu, 0.f);
            sc = rsqrtf(var + BN_EPS_F) * LD<TF>::f(gamma, t);
            sh = LD<TF>::f(beta, t) - mu * sc;
        }
        s_sc[t] = sc; s_sh[t] = sh;
    }
    __syncthreads();
    float lo = apply ? 0.f : -__builtin_inff();

    if (blockIdx.x < poolCnt) {
        // ---- pool role (red aliased into s_big4: 16*128*4 = 8KB) ----
        float (*red)[DD] = (float (*)[DD])s_big4;
        int g = blockIdx.x;
        int rlo = gstart[g], rhi = gstart[g + 1];
        int c = t & 15, rg = t >> 4;
        int d0 = c * 8;
        float sc8[8], sh8[8];
        #pragma unroll
        for (int j = 0; j < 8; ++j) { sc8[j] = s_sc[d0 + j]; sh8[j] = s_sh[d0 + j]; }
        float acc[8] = {0.f, 0.f, 0.f, 0.f, 0.f, 0.f, 0.f, 0.f};
        for (int i = rlo + rg; i < rhi; i += 16) {
            union { uint4 u; u16 us[8]; } v;
            v.u = *(const uint4*)(h + ((size_t)i << 7) + d0);
            #pragma unroll
            for (int j = 0; j < 8; ++j) {
                float f = __uint_as_float((u32)v.us[j] << 16) * sc8[j] + sh8[j];
                acc[j] += fmaxf(f, lo);
            }
        }
        #pragma unroll
        for (int j = 0; j < 8; ++j) red[rg][d0 + j] = acc[j];
        __syncthreads();
        if (t < DD) {
            float s = 0.f;
            #pragma unroll
            for (int k = 0; k < 16; ++k) s += red[k][t];
            pooled_l[g * DD + t] = s;
        }
        return;
    }

    // ---- phase A: gather into LDS r-tile (one node per 16-lane group) ----
    bf16* rt = (bf16*)s_big4;
    int grp = t >> 4, c = t & 15;
    int d0 = c << 3;
    float sc8[8], sh8[8];
    #pragma unroll
    for (int j = 0; j < 8; ++j) { sc8[j] = s_sc[d0 + j]; sh8[j] = s_sh[d0 + j]; }
    int nbase = (blockIdx.x - poolCnt) * TM;
    int node = nbase + grp;
    {
        union { uint4 u; bf16 b8[8]; } o;
        if (node < N) {
            int beg = row_ptr[node], end = row_ptr[node + 1];
            // self-row + norm_in issued early: overlap with edge chunk latency
            uint4 svu = *(const uint4*)(h + ((size_t)node << 7) + d0);
            float ni = 0.9f * norm_in[node];
            float acc[8] = {0.f, 0.f, 0.f, 0.f, 0.f, 0.f, 0.f, 0.f};
            #pragma unroll 1
            for (int e = beg; e < end; e += EC) {
                int cs[EC]; uint4 hv[EC]; float no[EC];
                #pragma unroll
                for (int k = 0; k < EC; ++k) {
                    int ee = e + k;
                    cs[k] = col[ee < end ? ee : end - 1];   // clamped (pad dupes last edge)
                }
                #pragma unroll
                for (int k = 0; k < EC; ++k)
                    hv[k] = *(const uint4*)(h + ((size_t)cs[k] << 7) + d0);
                #pragma unroll
                for (int k = 0; k < EC; ++k)
                    no[k] = (e + k < end) ? norm_out[cs[k]] : 0.f;  // zero-weight pad
                #pragma unroll
                for (int k = 0; k < EC; ++k) {
                    union { uint4 u; u16 us[8]; } v;
                    v.u = hv[k];
                    float nn = no[k];
                    #pragma unroll
                    for (int j = 0; j < 8; ++j) {
                        float f = __uint_as_float((u32)v.us[j] << 16) * sc8[j] + sh8[j];
                        acc[j] += fmaxf(f, lo) * nn;
                    }
                }
            }
            union { uint4 u; u16 us[8]; } sv;
            sv.u = svu;
            #pragma unroll
            for (int j = 0; j < 8; ++j) {
                float f = __uint_as_float((u32)sv.us[j] << 16) * sc8[j] + sh8[j];
                f = fmaxf(f, lo);
                o.b8[j] = __float2bfloat16(ni * acc[j] + 0.1f * f);
            }
        } else {
            o.u = make_uint4(0u, 0u, 0u, 0u);   // pad rows: zero (outputs masked anyway)
        }
        *(uint4*)(rt + (size_t)grp * RS + d0) = o.u;
    }
    __syncthreads();

    // ---- phase B: GEMM from LDS A-tile (M=16; wave w -> cols [32w, 32w+32)) ----
    int w = t >> 6, lane = t & 63;
    int q = lane >> 4, cc = lane & 15;
    f32x4v acc2[2];
    acc2[0] = (f32x4v){0.f, 0.f, 0.f, 0.f};
    acc2[1] = (f32x4v){0.f, 0.f, 0.f, 0.f};
    #pragma unroll
    for (int ks = 0; ks < 4; ++ks) {
        int k0 = ks * 32 + q * 8;
        union { uint4 u; bf16x8v v; } a0;
        a0.u = *(const uint4*)(rt + (size_t)cc * RS + k0);
        #pragma unroll
        for (int ct = 0; ct < 2; ++ct) {
            union { uint4 u; bf16x8v v; } bb;
            bb.u = *(const uint4*)(wt + (size_t)(w * 32 + ct * 16 + cc) * WSTRIDE + k0);
            acc2[ct] = __builtin_amdgcn_mfma_f32_16x16x32_bf16(a0.v, bb.v, acc2[ct], 0, 0, 0);
        }
    }
    // epilogue: C layout col = lane&15, row = quad*4 + reg  [m89-verified]
    // stats via NREP-replicated atomics (no LDS reduction pass needed)
    float* statsR = stats + (size_t)(blockIdx.x & (NREP - 1)) * 2 * DD;
    #pragma unroll
    for (int ct = 0; ct < 2; ++ct) {
        int coln = w * 32 + ct * 16 + cc;
        float bs = biasf[coln];
        float s1 = 0.f, s2 = 0.f;
        #pragma unroll
        for (int reg = 0; reg < 4; ++reg) {
            size_t row = (size_t)nbase + q * 4 + reg;
            float v = acc2[ct][reg] + bs;
            if (row < (size_t)N) {
                h_out[(row << 7) + coln] = __float2bfloat16(v);
                s1 += v;
                s2 += v * v;
            }
        }
        s1 += __shfl_xor(s1, 16, 64); s1 += __shfl_xor(s1, 32, 64);
        s2 += __shfl_xor(s2, 16, 64); s2 += __shfl_xor(s2, 32, 64);
        if (q == 0) {
            atomicAdd(&statsR[coln], s1);
            atomicAdd(&statsR[DD + coln], s2);
        }
    }
}

__global__ void k_fused(const bf16* __restrict__ h, const int* __restrict__ row_ptr,
        const int* __restrict__ col, const float* __restrict__ norm_out,
        const float* __restrict__ norm_in, const float* __restrict__ statsP,
        const void* bn_g, const void* bn_b, int laff, int apply,
        const int* __restrict__ gstart, float* __restrict__ pooled_l, int poolCnt,
        const int* __restrict__ flag, const bf16* __restrict__ wt,
        const float* __restrict__ biasf, bf16* __restrict__ h_out,
        float* __restrict__ stats, int N) {
    __shared__ float s_sc[DD];
    __shared__ float s_sh[DD];
    __shared__ uint4 s_big4[512];   // 8KB: pool-red [16][128]f32 / gather r-tile [16][136]bf16
    int bfv = *flag;
    size_t esz = bfv ? 2u : 4u;
    const char* gp = (const char*)bn_g + (size_t)laff * DD * esz;
    const char* bp = (const char*)bn_b + (size_t)laff * DD * esz;
    if (bfv) fused_body<bf16 >(h, row_ptr, col, norm_out, norm_in, statsP, gp, bp,
                               apply, gstart, pooled_l, poolCnt, wt, biasf, h_out, stats, N,
                               s_sc, s_sh, s_big4);
    else     fused_body<float>(h, row_ptr, col, norm_out, norm_in, statsP, gp, bp,
                               apply, gstart, pooled_l, poolCnt, wt, biasf, h_out, stats, N,
                               s_sc, s_sh, s_big4);
}

// ---------------- head (parallelized over 128 dims) ----------------

template<typename TF>
__device__ __forceinline__ void head_body(const float* __restrict__ pooled,
        const void* lin_w, const void* lin_b, void* out,
        float* red, float* scv, float* lse) {
    int g = blockIdx.x;   // 200
    int t = threadIdx.x;  // 128
    float part[10] = {0.f, 0.f, 0.f, 0.f, 0.f, 0.f, 0.f, 0.f, 0.f, 0.f};
    float mp = 0.f;
    for (int l = 0; l < NL + 1; ++l) {
        float pl = pooled[(size_t)(l * NG + g) * DD + t];
        if (l > 0) mp += pl;
        #pragma unroll
        for (int o = 0; o < 10; ++o)
            part[o] += pl * LD<TF>::f(lin_w, (size_t)l * DD * 10 + (size_t)t * 10 + o);
    }
    #pragma unroll
    for (int o = 0; o < 10; ++o) red[t * 10 + o] = part[o];
    __syncthreads();
    for (int off = 64; off >= 1; off >>= 1) {
        if (t < off) {
            #pragma unroll
            for (int o = 0; o < 10; ++o) red[t * 10 + o] += red[(t + off) * 10 + o];
        }
        __syncthreads();
    }
    if (t < 10) {
        float s = red[t];
        for (int l = 0; l < NL + 1; ++l) s += LD<TF>::f(lin_b, l * 10 + t);
        scv[t] = s;
    }
    __syncthreads();
    if (t == 0) {
        float m = scv[0];
        for (int o = 1; o < 10; ++o) m = fmaxf(m, scv[o]);
        float su = 0.f;
        for (int o = 0; o < 10; ++o) su += expf(scv[o] - m);
        *lse = m + logf(su);
    }
    __syncthreads();
    if (t < 10) ST<TF>::s(out, g * 10 + t, scv[t] - *lse);
    ST<TF>::s(out, NG * 10 + (size_t)g * DD + t, mp * 0.2f);
}

__global__ void k_head(const float* __restrict__ pooled, const int* __restrict__ flag,
        const void* lin_w, const void* lin_b, void* out) {
    __shared__ float red[128 * 10];
    __shared__ float scv[10];
    __shared__ float lse;
    if (*flag) head_body<bf16 >(pooled, lin_w, lin_b, out, red, scv, &lse);
    else       head_body<float>(pooled, lin_w, lin_b, out, red, scv, &lse);
}

// ---------------- launch ----------------

extern "C" void kernel_launch(void* const* d_in, const int* in_sizes, int n_in,
                              void* d_out, int out_size, void* d_ws, size_t ws_size,
                              hipStream_t stream) {
    const void* feat  = d_in[0];
    const int*  src   = (const int*)d_in[1];
    const int*  dst   = (const int*)d_in[2];
    const int*  gid   = (const int*)d_in[3];
    const void* gcn_w = d_in[4];
    const void* gcn_b = d_in[5];
    const void* bn_g  = d_in[6];
    const void* bn_b  = d_in[7];
    const void* lin_w = d_in[8];
    const void* lin_b = d_in[9];
    const int N = in_sizes[0] / DD;   // 100000
    const int E = in_sizes[1];        // 600000
    const int Mpad = ((N + 127) / 128) * 128;

    char* wsb = (char*)d_ws;
    size_t off = 0;
    auto carve = [&](size_t bytes) -> void* {
        void* p = wsb + off;
        off = (off + bytes + 255) & ~(size_t)255;
        return p;
    };
    int*   flag     = (int*)carve(4);
    // zeroed region: deg_out .. statsAll (one memset)
    int*   deg_out  = (int*)carve((size_t)N * 4);
    int*   deg_in   = (int*)carve((size_t)N * 4);
    float* statsAll = (float*)carve((size_t)NL * NREP * 2 * DD * 4);
    // un-zeroed scratch
    int*   row_ptr  = (int*)carve((size_t)(N + 1) * 4);
    int*   cursor   = (int*)carve((size_t)N * 4);
    int*   col      = (int*)carve((size_t)E * 4);
    int*   bsum     = (int*)carve(1024 * 4);
    int*   gstart   = (int*)carve((size_t)(NG + 1) * 4);
    float* norm_out = (float*)carve((size_t)N * 4);
    float* norm_in  = (float*)carve((size_t)N * 4);
    bf16*  wtp      = (bf16*)carve((size_t)NL * WELEMS * 2);
    float* biasp    = (float*)carve((size_t)NL * DD * 4);
    float* pooled   = (float*)carve((size_t)(NL + 1) * NG * DD * 4);
    bf16*  hA       = (bf16*)carve((size_t)Mpad * DD * 2);
    bf16*  hB       = (bf16*)carve((size_t)Mpad * DD * 2);

    if (off > ws_size) return;   // guard: leave d_out zeroed (distinguishable)

    hipMemsetAsync(deg_out, 0,
                   (size_t)((char*)statsAll - (char*)deg_out) + (size_t)NL * NREP * 2 * DD * 4,
                   stream);

    const int HB = ((E >> 2) + 255) / 256;   // hist blocks: 4 edges/thread
    k_init<<<CVT_BLOCKS + HB + NL + 1, 256, 0, stream>>>(
        src, dst, deg_out, deg_in, E, (const u16*)bn_g, flag,
        feat, gcn_w, gcn_b, gid, gstart, wtp, biasp, hA, N, HB);

    int B = (N + 1023) / 1024;
    k_reduce_chunks<<<B, 256, 0, stream>>>(deg_in, bsum, N);
    k_scan_bsum<<<1, 128, 0, stream>>>(bsum, B, row_ptr, N, E);
    k_scan_chunks<<<B, 256, 0, stream>>>(deg_in, deg_out, bsum, row_ptr, cursor,
                                         norm_out, norm_in, N);
    k_fill_csr<<<((E >> 2) + 255) / 256, 256, 0, stream>>>(src, dst, cursor, col, E);

    const int GBLK = (N + TM - 1) / TM;   // gather+gemm blocks: TM nodes each
    bf16* bufs[2] = { hA, hB };
    for (int l = 0; l < NL; ++l) {
        bf16* hin  = bufs[l & 1];
        bf16* hout = bufs[(l + 1) & 1];
        float* stats  = statsAll + (size_t)l * NREP * 2 * DD;                      // written by layer l
        float* statsP = statsAll + (size_t)(l > 0 ? l - 1 : 0) * NREP * 2 * DD;    // prev layer's
        k_fused<<<NG + GBLK, 256, 0, stream>>>(
            hin, row_ptr, col, norm_out, norm_in, statsP, bn_g, bn_b,
            l > 0 ? l - 1 : 0, l > 0 ? 1 : 0, gstart,
            pooled + (size_t)l * NG * DD, NG, flag,
            wtp + (size_t)l * WELEMS, biasp + (size_t)l * DD, hout, stats, N);
    }

    // final pool: hidden_rep[NL] from layer NL-1 output (stats[NL-1], bn[NL-1]); pool-only grid
    k_fused<<<NG, 256, 0, stream>>>(
        bufs[NL & 1], row_ptr, col, norm_out, norm_in,
        statsAll + (size_t)(NL - 1) * NREP * 2 * DD, bn_g, bn_b, NL - 1, 1, gstart,
        pooled + (size_t)NL * NG * DD, NG, flag,
        wtp, biasp, bufs[(NL + 1) & 1], statsAll + (size_t)(NL - 1) * NREP * 2 * DD, N);

    k_head<<<NG, DD, 0, stream>>>(pooled, flag, lin_w, lin_b, d_out);
}